// Round 12
// baseline (149.839 us; speedup 1.0000x reference)
//
#include <hip/hip_runtime.h>

#define Bn 4
#define Qn 128
#define Kn 1024
#define Dn 512   // DQ = DK = DV = 512
#define Hn 256

// tanh(x) = 1 - 2/(1 + e^{2x}).  Inf-safe: e->inf => rcp(inf)=0 => 1.
__device__ __forceinline__ float fast_tanh(float x) {
    float e = __expf(2.0f * x);
    return 1.0f - 2.0f * __builtin_amdgcn_rcpf(1.0f + e);
}

// ---------------------------------------------------------------------------
// Kernel 1: projections GEMM [4608x512]@[512x256], 64x64 tile, BK=64.
// Block-level split-K (kc in {0,1}, 256 deep, disjoint proj0/proj1 partials
// summed by consumers) + 8-wave intra-block split (waves 0-3: kk 0..31,
// waves 4-7: kk 32..63) + LDS merge. Blocks 0..127 zero `out`, block 0 zeros
// rowsum at entry (before any masked early-return) -> no memset dispatches.
// ---------------------------------------------------------------------------
#define PBK 64

__global__ __launch_bounds__(512) void proj_kernel(
    const float* __restrict__ queries, const float* __restrict__ keys,
    const float* __restrict__ Wq, const float* __restrict__ Wk,
    const int* __restrict__ valid_lens,
    float* __restrict__ proj0, float* __restrict__ proj1,
    float* __restrict__ rowsum, float* __restrict__ out)
{
    const int blk = blockIdx.x;         // ((mt*4)+nt)*2 + kc
    const int t = threadIdx.x;

    // ---- fused zeroing (must precede any early return) -------------------
    if (blk < 128) {                    // 128 blk * 512 thr * 16 B = 1 MB
        float4 z = {0.f, 0.f, 0.f, 0.f};
        ((float4*)out)[blk * 512 + t] = z;
        if (blk == 0) rowsum[t] = 0.f;  // 512 floats
    }

    const int kc = blk & 1;
    const int nt = (blk >> 1) & 3;
    const int mt = blk >> 3;            // 0..71
    const float* Asrc; const float* W;
    int m0, drow;
    if (mt < 8) {                       // query rows (512 = B*Q)
        m0 = mt * 64;
        drow = m0;
        Asrc = queries; W = Wq;
    } else {                            // key rows (4096 = B*K)
        int r0 = (mt - 8) * 64;
        int b = r0 >> 10;
        if ((r0 & 1023) >= valid_lens[b]) return;   // tile fully masked
        m0 = r0;
        drow = 512 + r0;
        Asrc = keys; W = Wk;
    }
    const int n0 = nt * 64;
    const int k0 = kc * 256;            // this block's K-chunk
    float* Dst = (kc ? proj1 : proj0) + (size_t)drow * Hn;

    __shared__ float s_a[PBK][68];      // A^T tile [k][m], pad 68 (17408 B)
    __shared__ float s_b[PBK][64];      // B tile   [k][n]   (16384 B)

    const int tt   = t & 255;           // position within k-half
    const int kh   = t >> 8;            // 0 -> kk 0..31, 1 -> kk 32..63
    const int trow = tt >> 4;           // 0..15 (x4 m)
    const int tcol = tt & 15;           // 0..15 (x4 n)
    const int kklo = kh << 5;

    const int lrow = t >> 4;            // 0..31 (staging row)
    const int lc4  = t & 15;

    float acc[4][4] = {{0.f}};
    float4 ra[2], rb[2];

    #pragma unroll
    for (int i = 0; i < 2; ++i) {       // preload kt=0
        ra[i] = *(const float4*)(Asrc + (size_t)(m0 + lrow + i * 32) * Dn + k0 + lc4 * 4);
        rb[i] = *(const float4*)(W + (size_t)(k0 + lrow + i * 32) * Hn + n0 + lc4 * 4);
    }

    for (int kt = 0; kt < 4; ++kt) {
        __syncthreads();                // prev compute done before overwrite
        #pragma unroll
        for (int i = 0; i < 2; ++i) {   // regs -> LDS (waits vmcnt here)
            int row = lrow + i * 32;
            s_a[lc4 * 4 + 0][row] = ra[i].x;
            s_a[lc4 * 4 + 1][row] = ra[i].y;
            s_a[lc4 * 4 + 2][row] = ra[i].z;
            s_a[lc4 * 4 + 3][row] = ra[i].w;
            *(float4*)&s_b[row][lc4 * 4] = rb[i];
        }
        __syncthreads();
        if (kt < 3) {                   // prefetch kt+1 (overlaps compute)
            const int d0n = k0 + (kt + 1) * PBK;
            #pragma unroll
            for (int i = 0; i < 2; ++i) {
                ra[i] = *(const float4*)(Asrc + (size_t)(m0 + lrow + i * 32) * Dn + d0n + lc4 * 4);
                rb[i] = *(const float4*)(W + (size_t)(d0n + lrow + i * 32) * Hn + n0 + lc4 * 4);
            }
        }
        #pragma unroll
        for (int kk = 0; kk < 32; ++kk) {
            float4 a4 = *(const float4*)&s_a[kklo + kk][trow * 4];
            float4 b4 = *(const float4*)&s_b[kklo + kk][tcol * 4];
            float a[4] = {a4.x, a4.y, a4.z, a4.w};
            float b[4] = {b4.x, b4.y, b4.z, b4.w};
            #pragma unroll
            for (int i = 0; i < 4; ++i)
                #pragma unroll
                for (int j = 0; j < 4; ++j)
                    acc[i][j] += a[i] * b[j];
        }
    }

    // merge the two k-halves through LDS (s_a region: 256*17 floats,
    // stride 17 keeps the scalar accesses conflict-free)
    __syncthreads();
    float* red = &s_a[0][0];
    if (kh) {
        #pragma unroll
        for (int i = 0; i < 4; ++i)
            #pragma unroll
            for (int j = 0; j < 4; ++j)
                red[tt * 17 + i * 4 + j] = acc[i][j];
    }
    __syncthreads();
    if (!kh) {
        #pragma unroll
        for (int i = 0; i < 4; ++i) {
            float4 o;
            o.x = acc[i][0] + red[tt * 17 + i * 4 + 0];
            o.y = acc[i][1] + red[tt * 17 + i * 4 + 1];
            o.z = acc[i][2] + red[tt * 17 + i * 4 + 2];
            o.w = acc[i][3] + red[tt * 17 + i * 4 + 3];
            *(float4*)(Dst + (size_t)(trow * 4 + i) * Hn + n0 + tcol * 4) = o;
        }
    }
}

// ---------------------------------------------------------------------------
// Kernel 2: scores. v7 (validated R10/R11): grid 2048 = kt(64, HIGH bits) x
// b(4) x qp(8: 16 q-rows), LDS 35.9 KB -> 4 blocks/CU, balanced under vlen
// masking. Wave = 16 kloc x 4 hq, 4 q-rows/wave. [row][hq][68] conflict-free
// LDS, max-free exp (|s| <= sum|wv|), atomic rowsum.
// ---------------------------------------------------------------------------
#define HQS 68          // hq quarter stride (floats): 4-bank offset
#define QRS 272         // row stride = 4 * HQS

__global__ __launch_bounds__(256) void score_kernel(
    const float* __restrict__ proj0, const float* __restrict__ proj1,
    const float* __restrict__ wv, const int* __restrict__ valid_lens,
    float* __restrict__ escores, float* __restrict__ rowsum)
{
    const int blk = blockIdx.x;             // kt*32 + b*8 + qp  (kt HIGH)
    const int qp = blk & 7;
    const int b  = (blk >> 3) & 3;
    const int kt = blk >> 5;                // 0..63
    const int vlen = valid_lens[b];
    const int k0 = kt * 16;
    if (k0 >= vlen) return;                 // fully-masked tile
    const int q0 = qp * 16;
    const int t = threadIdx.x;

    __shared__ float s_k[16 * QRS];         // 17408 B
    __shared__ float s_q[16 * QRS];         // 17408 B
    __shared__ float s_wv[QRS];             //  1088 B

    {
        const float4* k0p = (const float4*)(proj0 + ((size_t)(512 + b * Kn + k0)) * Hn);
        const float4* k1p = (const float4*)(proj1 + ((size_t)(512 + b * Kn + k0)) * Hn);
        #pragma unroll
        for (int i = 0; i < 4; ++i) {       // 16 rows x 64 float4
            int idx = t + i * 256;
            int row = idx >> 6, c4 = idx & 63;
            float4 a = k0p[idx], c = k1p[idx];
            a.x += c.x; a.y += c.y; a.z += c.z; a.w += c.w;
            *(float4*)&s_k[row * QRS + (c4 >> 4) * HQS + (c4 & 15) * 4] = a;
        }
        const float4* q0p = (const float4*)(proj0 + ((size_t)(b * Qn + q0)) * Hn);
        const float4* q1p = (const float4*)(proj1 + ((size_t)(b * Qn + q0)) * Hn);
        #pragma unroll
        for (int i = 0; i < 4; ++i) {       // 16 rows x 64 float4
            int idx = t + i * 256;
            int row = idx >> 6, c4 = idx & 63;
            float4 a = q0p[idx], c = q1p[idx];
            a.x += c.x; a.y += c.y; a.z += c.z; a.w += c.w;
            *(float4*)&s_q[row * QRS + (c4 >> 4) * HQS + (c4 & 15) * 4] = a;
        }
        if (t < 64)
            *(float4*)&s_wv[(t >> 4) * HQS + (t & 15) * 4] =
                ((const float4*)wv)[t];
    }
    __syncthreads();

    const int w = t >> 6, lane = t & 63;
    const int kloc = lane & 15, hq = lane >> 4;   // h-quarter: 64 h each
    const float4* kr = (const float4*)&s_k[kloc * QRS + hq * HQS];
    const float4* wr = (const float4*)&s_wv[hq * HQS];
    const float*  qb = &s_q[(size_t)(w * 4) * QRS + hq * HQS];

    float acc[4] = {0.f, 0.f, 0.f, 0.f};
    #pragma unroll 4
    for (int i = 0; i < 16; ++i) {          // 16 float4 = 64 h per lane
        float4 kv = kr[i];
        float4 wq = wr[i];
        #pragma unroll
        for (int qr = 0; qr < 4; ++qr) {
            float4 qv = *(const float4*)&qb[qr * QRS + i * 4];
            acc[qr] += wq.x * fast_tanh(qv.x + kv.x)
                     + wq.y * fast_tanh(qv.y + kv.y)
                     + wq.z * fast_tanh(qv.z + kv.z)
                     + wq.w * fast_tanh(qv.w + kv.w);
        }
    }
    const int k = k0 + kloc;
    #pragma unroll
    for (int qr = 0; qr < 4; ++qr) {
        float s = acc[qr];
        s += __shfl_xor(s, 16, 64);         // combine hq quarters
        s += __shfl_xor(s, 32, 64);
        float e = 0.f;
        if (lane < 16 && k < vlen) {
            e = __expf(s);
            escores[((size_t)(b * Qn + q0 + w * 4 + qr)) * Kn + k] = e;
        }
        e += __shfl_xor(e, 8, 64);
        e += __shfl_xor(e, 4, 64);
        e += __shfl_xor(e, 2, 64);
        e += __shfl_xor(e, 1, 64);
        if (lane == 0)
            atomicAdd(&rowsum[b * Qn + q0 + w * 4 + qr], e);
    }
}

// ---------------------------------------------------------------------------
// Kernel 3: AV + fused normalize. v9: occupancy 2x again for the cold path.
// R11 validated the mechanism (kc 8->16 = -7.3 us wall; doubling atomics
// was harmless). kc 16 -> 32 (32-k chunks): grid 1024 = b(4) x qt(8: 16 q)
// x kc(32), i.e. 4 blocks/CU / 4 waves/SIMD; each block's serial k-depth
// halves again. Atomics 4.2M -> 8.4M (~2 us L2, proven non-binding).
// s_e 2 KB. V-load unroll 8 (16 float2 in flight for cold-miss cover).
// escores staged with per-component k<vlen guard; fully-masked chunks skip.
// acc * rcp(rowsum) atomically into out (zeroed by proj).
// ---------------------------------------------------------------------------
__global__ __launch_bounds__(256) void av_kernel(
    const float* __restrict__ escores, const float* __restrict__ values,
    const float* __restrict__ rowsum, const int* __restrict__ valid_lens,
    float* __restrict__ out)
{
    const int blk = blockIdx.x;         // ((b*8 + qt)*32 + kc)
    const int kc = blk & 31;
    const int qt = (blk >> 5) & 7;
    const int b  = blk >> 8;
    const int vlen = valid_lens[b];
    const int kb = kc * 32;
    if (kb >= vlen) return;             // fully-masked chunk
    const int q0 = qt * 16;
    const int t = threadIdx.x;

    __shared__ float s_e[16 * 32];      // 2 KB
    if (t < 128) {                      // 16 rows x 8 float4 = 128 f4
        int row = t >> 3, c4 = t & 7;
        const float* esrc = escores + ((size_t)(b * Qn + q0 + row)) * Kn + kb + c4 * 4;
        int kbase = kb + c4 * 4;
        float4 ev;
        ev.x = (kbase + 0 < vlen) ? esrc[0] : 0.f;
        ev.y = (kbase + 1 < vlen) ? esrc[1] : 0.f;
        ev.z = (kbase + 2 < vlen) ? esrc[2] : 0.f;
        ev.w = (kbase + 3 < vlen) ? esrc[3] : 0.f;
        *(float4*)&s_e[row * 32 + c4 * 4] = ev;
    }
    __syncthreads();

    const int d0 = t * 2;               // 256 threads cover D=512
    const float* vb = values + ((size_t)(b * Kn + kb)) * Dn + d0;
    float accx[16], accy[16];
    #pragma unroll
    for (int j = 0; j < 16; ++j) { accx[j] = 0.f; accy[j] = 0.f; }

    #pragma unroll 8
    for (int k = 0; k < 32; k += 4) {
        float2 v0 = *(const float2*)&vb[(size_t)(k + 0) * Dn];
        float2 v1 = *(const float2*)&vb[(size_t)(k + 1) * Dn];
        float2 v2 = *(const float2*)&vb[(size_t)(k + 2) * Dn];
        float2 v3 = *(const float2*)&vb[(size_t)(k + 3) * Dn];
        #pragma unroll
        for (int j = 0; j < 16; ++j) {
            float4 e4 = *(const float4*)&s_e[j * 32 + k];   // uniform bcast
            accx[j] += e4.x * v0.x + e4.y * v1.x + e4.z * v2.x + e4.w * v3.x;
            accy[j] += e4.x * v0.y + e4.y * v1.y + e4.z * v2.y + e4.w * v3.y;
        }
    }
    float* op = out + ((size_t)(b * Qn + q0)) * Dn + d0;
    #pragma unroll
    for (int j = 0; j < 16; ++j) {
        float inv = __builtin_amdgcn_rcpf(rowsum[b * Qn + q0 + j]);
        atomicAdd(op + (size_t)j * Dn + 0, accx[j] * inv);
        atomicAdd(op + (size_t)j * Dn + 1, accy[j] * inv);
    }
}

// ---------------------------------------------------------------------------
extern "C" void kernel_launch(void* const* d_in, const int* in_sizes, int n_in,
                              void* d_out, int out_size, void* d_ws, size_t ws_size,
                              hipStream_t stream) {
    const float* queries    = (const float*)d_in[0];
    const float* keys       = (const float*)d_in[1];
    const float* values     = (const float*)d_in[2];
    const int*   valid_lens = (const int*)  d_in[3];
    const float* Wq         = (const float*)d_in[4];
    const float* Wk         = (const float*)d_in[5];
    const float* wv         = (const float*)d_in[6];
    float* out = (float*)d_out;

    // ws layout: proj partials rows 0..511 = qproj, 512..4607 = kproj
    const size_t PROJ_F = (size_t)4608 * Hn;          // 1179648 floats each
    float* proj0   = (float*)d_ws;
    float* proj1   = proj0 + PROJ_F;
    float* escores = proj1 + PROJ_F;                  // [B*Q, K] 524288 f
    float* rowsum  = escores + (size_t)Bn * Qn * Kn;  // [B*Q]       512 f

    // 3 dispatches, zero memsets (zeroing fused into proj_kernel)
    proj_kernel<<<576, 512, 0, stream>>>(queries, keys, Wq, Wk, valid_lens,
                                         proj0, proj1, rowsum, out);
    score_kernel<<<2048, 256, 0, stream>>>(proj0, proj1, wv, valid_lens,
                                           escores, rowsum);
    av_kernel<<<1024, 256, 0, stream>>>(escores, values, rowsum, valid_lens,
                                        out);
}

// Round 13
// 146.677 us; speedup vs baseline: 1.0216x; 1.0216x over previous
//
#include <hip/hip_runtime.h>

#define Bn 4
#define Qn 128
#define Kn 1024
#define Dn 512   // DQ = DK = DV = 512
#define Hn 256

// tanh(x) = 1 - 2/(1 + e^{2x}).  Inf-safe: e->inf => rcp(inf)=0 => 1.
__device__ __forceinline__ float fast_tanh(float x) {
    float e = __expf(2.0f * x);
    return 1.0f - 2.0f * __builtin_amdgcn_rcpf(1.0f + e);
}

// ---------------------------------------------------------------------------
// Kernel 1: projections GEMM [4608x512]@[512x256], 64x64 tile, BK=64.
// Block-level split-K (kc in {0,1}, 256 deep, disjoint proj0/proj1 partials
// summed by consumers) + 8-wave intra-block split (waves 0-3: kk 0..31,
// waves 4-7: kk 32..63) + LDS merge. Blocks 0..127 zero `out`, block 0 zeros
// rowsum at entry (before any masked early-return) -> no memset dispatches.
// ---------------------------------------------------------------------------
#define PBK 64

__global__ __launch_bounds__(512) void proj_kernel(
    const float* __restrict__ queries, const float* __restrict__ keys,
    const float* __restrict__ Wq, const float* __restrict__ Wk,
    const int* __restrict__ valid_lens,
    float* __restrict__ proj0, float* __restrict__ proj1,
    float* __restrict__ rowsum, float* __restrict__ out)
{
    const int blk = blockIdx.x;         // ((mt*4)+nt)*2 + kc
    const int t = threadIdx.x;

    // ---- fused zeroing (must precede any early return) -------------------
    if (blk < 128) {                    // 128 blk * 512 thr * 16 B = 1 MB
        float4 z = {0.f, 0.f, 0.f, 0.f};
        ((float4*)out)[blk * 512 + t] = z;
        if (blk == 0) rowsum[t] = 0.f;  // 512 floats
    }

    const int kc = blk & 1;
    const int nt = (blk >> 1) & 3;
    const int mt = blk >> 3;            // 0..71
    const float* Asrc; const float* W;
    int m0, drow;
    if (mt < 8) {                       // query rows (512 = B*Q)
        m0 = mt * 64;
        drow = m0;
        Asrc = queries; W = Wq;
    } else {                            // key rows (4096 = B*K)
        int r0 = (mt - 8) * 64;
        int b = r0 >> 10;
        if ((r0 & 1023) >= valid_lens[b]) return;   // tile fully masked
        m0 = r0;
        drow = 512 + r0;
        Asrc = keys; W = Wk;
    }
    const int n0 = nt * 64;
    const int k0 = kc * 256;            // this block's K-chunk
    float* Dst = (kc ? proj1 : proj0) + (size_t)drow * Hn;

    __shared__ float s_a[PBK][68];      // A^T tile [k][m], pad 68 (17408 B)
    __shared__ float s_b[PBK][64];      // B tile   [k][n]   (16384 B)

    const int tt   = t & 255;           // position within k-half
    const int kh   = t >> 8;            // 0 -> kk 0..31, 1 -> kk 32..63
    const int trow = tt >> 4;           // 0..15 (x4 m)
    const int tcol = tt & 15;           // 0..15 (x4 n)
    const int kklo = kh << 5;

    const int lrow = t >> 4;            // 0..31 (staging row)
    const int lc4  = t & 15;

    float acc[4][4] = {{0.f}};
    float4 ra[2], rb[2];

    #pragma unroll
    for (int i = 0; i < 2; ++i) {       // preload kt=0
        ra[i] = *(const float4*)(Asrc + (size_t)(m0 + lrow + i * 32) * Dn + k0 + lc4 * 4);
        rb[i] = *(const float4*)(W + (size_t)(k0 + lrow + i * 32) * Hn + n0 + lc4 * 4);
    }

    for (int kt = 0; kt < 4; ++kt) {
        __syncthreads();                // prev compute done before overwrite
        #pragma unroll
        for (int i = 0; i < 2; ++i) {   // regs -> LDS (waits vmcnt here)
            int row = lrow + i * 32;
            s_a[lc4 * 4 + 0][row] = ra[i].x;
            s_a[lc4 * 4 + 1][row] = ra[i].y;
            s_a[lc4 * 4 + 2][row] = ra[i].z;
            s_a[lc4 * 4 + 3][row] = ra[i].w;
            *(float4*)&s_b[row][lc4 * 4] = rb[i];
        }
        __syncthreads();
        if (kt < 3) {                   // prefetch kt+1 (overlaps compute)
            const int d0n = k0 + (kt + 1) * PBK;
            #pragma unroll
            for (int i = 0; i < 2; ++i) {
                ra[i] = *(const float4*)(Asrc + (size_t)(m0 + lrow + i * 32) * Dn + d0n + lc4 * 4);
                rb[i] = *(const float4*)(W + (size_t)(d0n + lrow + i * 32) * Hn + n0 + lc4 * 4);
            }
        }
        #pragma unroll
        for (int kk = 0; kk < 32; ++kk) {
            float4 a4 = *(const float4*)&s_a[kklo + kk][trow * 4];
            float4 b4 = *(const float4*)&s_b[kklo + kk][tcol * 4];
            float a[4] = {a4.x, a4.y, a4.z, a4.w};
            float b[4] = {b4.x, b4.y, b4.z, b4.w};
            #pragma unroll
            for (int i = 0; i < 4; ++i)
                #pragma unroll
                for (int j = 0; j < 4; ++j)
                    acc[i][j] += a[i] * b[j];
        }
    }

    // merge the two k-halves through LDS (s_a region: 256*17 floats,
    // stride 17 keeps the scalar accesses conflict-free)
    __syncthreads();
    float* red = &s_a[0][0];
    if (kh) {
        #pragma unroll
        for (int i = 0; i < 4; ++i)
            #pragma unroll
            for (int j = 0; j < 4; ++j)
                red[tt * 17 + i * 4 + j] = acc[i][j];
    }
    __syncthreads();
    if (!kh) {
        #pragma unroll
        for (int i = 0; i < 4; ++i) {
            float4 o;
            o.x = acc[i][0] + red[tt * 17 + i * 4 + 0];
            o.y = acc[i][1] + red[tt * 17 + i * 4 + 1];
            o.z = acc[i][2] + red[tt * 17 + i * 4 + 2];
            o.w = acc[i][3] + red[tt * 17 + i * 4 + 3];
            *(float4*)(Dst + (size_t)(trow * 4 + i) * Hn + n0 + tcol * 4) = o;
        }
    }
}

// ---------------------------------------------------------------------------
// Kernel 2: scores. v7 (validated R10/R11): grid 2048 = kt(64, HIGH bits) x
// b(4) x qp(8: 16 q-rows), LDS 35.9 KB -> 4 blocks/CU, balanced under vlen
// masking. Wave = 16 kloc x 4 hq, 4 q-rows/wave. [row][hq][68] conflict-free
// LDS, max-free exp (|s| <= sum|wv|), atomic rowsum.
// ---------------------------------------------------------------------------
#define HQS 68          // hq quarter stride (floats): 4-bank offset
#define QRS 272         // row stride = 4 * HQS

__global__ __launch_bounds__(256) void score_kernel(
    const float* __restrict__ proj0, const float* __restrict__ proj1,
    const float* __restrict__ wv, const int* __restrict__ valid_lens,
    float* __restrict__ escores, float* __restrict__ rowsum)
{
    const int blk = blockIdx.x;             // kt*32 + b*8 + qp  (kt HIGH)
    const int qp = blk & 7;
    const int b  = (blk >> 3) & 3;
    const int kt = blk >> 5;                // 0..63
    const int vlen = valid_lens[b];
    const int k0 = kt * 16;
    if (k0 >= vlen) return;                 // fully-masked tile
    const int q0 = qp * 16;
    const int t = threadIdx.x;

    __shared__ float s_k[16 * QRS];         // 17408 B
    __shared__ float s_q[16 * QRS];         // 17408 B
    __shared__ float s_wv[QRS];             //  1088 B

    {
        const float4* k0p = (const float4*)(proj0 + ((size_t)(512 + b * Kn + k0)) * Hn);
        const float4* k1p = (const float4*)(proj1 + ((size_t)(512 + b * Kn + k0)) * Hn);
        #pragma unroll
        for (int i = 0; i < 4; ++i) {       // 16 rows x 64 float4
            int idx = t + i * 256;
            int row = idx >> 6, c4 = idx & 63;
            float4 a = k0p[idx], c = k1p[idx];
            a.x += c.x; a.y += c.y; a.z += c.z; a.w += c.w;
            *(float4*)&s_k[row * QRS + (c4 >> 4) * HQS + (c4 & 15) * 4] = a;
        }
        const float4* q0p = (const float4*)(proj0 + ((size_t)(b * Qn + q0)) * Hn);
        const float4* q1p = (const float4*)(proj1 + ((size_t)(b * Qn + q0)) * Hn);
        #pragma unroll
        for (int i = 0; i < 4; ++i) {       // 16 rows x 64 float4
            int idx = t + i * 256;
            int row = idx >> 6, c4 = idx & 63;
            float4 a = q0p[idx], c = q1p[idx];
            a.x += c.x; a.y += c.y; a.z += c.z; a.w += c.w;
            *(float4*)&s_q[row * QRS + (c4 >> 4) * HQS + (c4 & 15) * 4] = a;
        }
        if (t < 64)
            *(float4*)&s_wv[(t >> 4) * HQS + (t & 15) * 4] =
                ((const float4*)wv)[t];
    }
    __syncthreads();

    const int w = t >> 6, lane = t & 63;
    const int kloc = lane & 15, hq = lane >> 4;   // h-quarter: 64 h each
    const float4* kr = (const float4*)&s_k[kloc * QRS + hq * HQS];
    const float4* wr = (const float4*)&s_wv[hq * HQS];
    const float*  qb = &s_q[(size_t)(w * 4) * QRS + hq * HQS];

    float acc[4] = {0.f, 0.f, 0.f, 0.f};
    #pragma unroll 4
    for (int i = 0; i < 16; ++i) {          // 16 float4 = 64 h per lane
        float4 kv = kr[i];
        float4 wq = wr[i];
        #pragma unroll
        for (int qr = 0; qr < 4; ++qr) {
            float4 qv = *(const float4*)&qb[qr * QRS + i * 4];
            acc[qr] += wq.x * fast_tanh(qv.x + kv.x)
                     + wq.y * fast_tanh(qv.y + kv.y)
                     + wq.z * fast_tanh(qv.z + kv.z)
                     + wq.w * fast_tanh(qv.w + kv.w);
        }
    }
    const int k = k0 + kloc;
    #pragma unroll
    for (int qr = 0; qr < 4; ++qr) {
        float s = acc[qr];
        s += __shfl_xor(s, 16, 64);         // combine hq quarters
        s += __shfl_xor(s, 32, 64);
        float e = 0.f;
        if (lane < 16 && k < vlen) {
            e = __expf(s);
            escores[((size_t)(b * Qn + q0 + w * 4 + qr)) * Kn + k] = e;
        }
        e += __shfl_xor(e, 8, 64);
        e += __shfl_xor(e, 4, 64);
        e += __shfl_xor(e, 2, 64);
        e += __shfl_xor(e, 1, 64);
        if (lane == 0)
            atomicAdd(&rowsum[b * Qn + q0 + w * 4 + qr], e);
    }
}

// ---------------------------------------------------------------------------
// Kernel 3: AV + fused normalize. REVERTED to the R11-proven optimum
// (kc=16, grid 512 = b(4) x qt(8: 16 q) x kc(16: 64-k chunks), 2 blocks/CU).
// R12's kc=32 experiment REGRESSED (+5.5 us): per-block fixed costs
// (escores staging, 2x atomics, launch/drain of 1024 blocks) outgrew the
// marginal latency-hiding gain. Occupancy lever is at its optimum here.
// Thread covers 2 d (float2 V loads), 16q x 2d per thread, k-unroll 4.
// escores staged with per-component k<vlen guard; fully-masked chunks skip.
// acc * rcp(rowsum) atomically into out (zeroed by proj).
// ---------------------------------------------------------------------------
__global__ __launch_bounds__(256) void av_kernel(
    const float* __restrict__ escores, const float* __restrict__ values,
    const float* __restrict__ rowsum, const int* __restrict__ valid_lens,
    float* __restrict__ out)
{
    const int blk = blockIdx.x;         // ((b*8 + qt)*16 + kc)
    const int kc = blk & 15;
    const int qt = (blk >> 4) & 7;
    const int b  = blk >> 7;
    const int vlen = valid_lens[b];
    const int kb = kc * 64;
    if (kb >= vlen) return;             // fully-masked chunk
    const int q0 = qt * 16;
    const int t = threadIdx.x;

    __shared__ float s_e[16 * 64];      // 4 KB
    {                                   // 16 rows x 16 float4 = 256 f4
        int row = t >> 4, c4 = t & 15;
        const float* esrc = escores + ((size_t)(b * Qn + q0 + row)) * Kn + kb + c4 * 4;
        int kbase = kb + c4 * 4;
        float4 ev;
        ev.x = (kbase + 0 < vlen) ? esrc[0] : 0.f;
        ev.y = (kbase + 1 < vlen) ? esrc[1] : 0.f;
        ev.z = (kbase + 2 < vlen) ? esrc[2] : 0.f;
        ev.w = (kbase + 3 < vlen) ? esrc[3] : 0.f;
        *(float4*)&s_e[row * 64 + c4 * 4] = ev;
    }
    __syncthreads();

    const int d0 = t * 2;               // 256 threads cover D=512
    const float* vb = values + ((size_t)(b * Kn + kb)) * Dn + d0;
    float accx[16], accy[16];
    #pragma unroll
    for (int j = 0; j < 16; ++j) { accx[j] = 0.f; accy[j] = 0.f; }

    #pragma unroll 4
    for (int k = 0; k < 64; k += 4) {
        float2 v0 = *(const float2*)&vb[(size_t)(k + 0) * Dn];
        float2 v1 = *(const float2*)&vb[(size_t)(k + 1) * Dn];
        float2 v2 = *(const float2*)&vb[(size_t)(k + 2) * Dn];
        float2 v3 = *(const float2*)&vb[(size_t)(k + 3) * Dn];
        #pragma unroll
        for (int j = 0; j < 16; ++j) {
            float4 e4 = *(const float4*)&s_e[j * 64 + k];   // uniform bcast
            accx[j] += e4.x * v0.x + e4.y * v1.x + e4.z * v2.x + e4.w * v3.x;
            accy[j] += e4.x * v0.y + e4.y * v1.y + e4.z * v2.y + e4.w * v3.y;
        }
    }
    float* op = out + ((size_t)(b * Qn + q0)) * Dn + d0;
    #pragma unroll
    for (int j = 0; j < 16; ++j) {
        float inv = __builtin_amdgcn_rcpf(rowsum[b * Qn + q0 + j]);
        atomicAdd(op + (size_t)j * Dn + 0, accx[j] * inv);
        atomicAdd(op + (size_t)j * Dn + 1, accy[j] * inv);
    }
}

// ---------------------------------------------------------------------------
extern "C" void kernel_launch(void* const* d_in, const int* in_sizes, int n_in,
                              void* d_out, int out_size, void* d_ws, size_t ws_size,
                              hipStream_t stream) {
    const float* queries    = (const float*)d_in[0];
    const float* keys       = (const float*)d_in[1];
    const float* values     = (const float*)d_in[2];
    const int*   valid_lens = (const int*)  d_in[3];
    const float* Wq         = (const float*)d_in[4];
    const float* Wk         = (const float*)d_in[5];
    const float* wv         = (const float*)d_in[6];
    float* out = (float*)d_out;

    // ws layout: proj partials rows 0..511 = qproj, 512..4607 = kproj
    const size_t PROJ_F = (size_t)4608 * Hn;          // 1179648 floats each
    float* proj0   = (float*)d_ws;
    float* proj1   = proj0 + PROJ_F;
    float* escores = proj1 + PROJ_F;                  // [B*Q, K] 524288 f
    float* rowsum  = escores + (size_t)Bn * Qn * Kn;  // [B*Q]       512 f

    // 3 dispatches, zero memsets (zeroing fused into proj_kernel)
    proj_kernel<<<576, 512, 0, stream>>>(queries, keys, Wq, Wk, valid_lens,
                                         proj0, proj1, rowsum, out);
    score_kernel<<<2048, 256, 0, stream>>>(proj0, proj1, wv, valid_lens,
                                           escores, rowsum);
    av_kernel<<<512, 256, 0, stream>>>(escores, values, rowsum, valid_lens,
                                       out);
}